// Round 4
// baseline (185.850 us; speedup 1.0000x reference)
//
#include <hip/hip_runtime.h>

#define NUM_EMB 1024
#define DIM     256
#define NPIX    32768      // 32 * 32 * 32
#define NELEM   8388608    // 32 * 256 * 32 * 32

typedef unsigned short u16;
typedef unsigned int   u32;
typedef __attribute__((ext_vector_type(8))) short bf16x8;
typedef __attribute__((ext_vector_type(4))) float f32x4;
typedef __attribute__((ext_vector_type(16))) float f32x16;

__device__ __forceinline__ u16 f32_bf16(float f) {
    u32 u = __float_as_uint(f);
    u += 0x7fffu + ((u >> 16) & 1u);          // round-to-nearest-even
    return (u16)(u >> 16);
}
__device__ __forceinline__ float bf16_f32(u16 h) {
    return __uint_as_float((u32)h << 16);
}

// ===========================================================================
// MFMA path
// ===========================================================================

// ---------------------------------------------------------------------------
// prep_x: split x (f32, (32,256,32,32)) into 3 bf16 arrays in frag-major
// layout [kc(8)][kb(4)][px(32768)][8k] and compute |x|^2 per pixel.
// ---------------------------------------------------------------------------
__global__ __launch_bounds__(256) void k_prep_x(const float* __restrict__ x,
        u16* __restrict__ X0, u16* __restrict__ X1, u16* __restrict__ X2,
        float* __restrict__ nx_out)
{
    __shared__ float nxp[4][64];
    const int t  = threadIdx.x;
    const int p  = t & 63;
    const int cq = t >> 6;
    const int bi = blockIdx.x;            // 512
    const int b  = bi >> 4;
    const int hw = ((bi & 15) << 6) + p;
    const float* xp = x + (((size_t)(b * 256 + cq * 64)) << 10) + hw;
    float s = 0.f;
    for (int i0 = 0; i0 < 64; i0 += 8) {
        u32 q0[4], q1[4], q2[4];
#pragma unroll
        for (int j = 0; j < 8; ++j) {
            float v = xp[(size_t)(i0 + j) << 10];
            s = fmaf(v, v, s);
            u16 h0 = f32_bf16(v);
            float r1 = v - bf16_f32(h0);          // exact (Sterbenz)
            u16 h1 = f32_bf16(r1);
            u16 h2 = f32_bf16(r1 - bf16_f32(h1)); // residual <= 2^-27 |v|
            if ((j & 1) == 0) { q0[j>>1] = h0; q1[j>>1] = h1; q2[j>>1] = h2; }
            else { q0[j>>1] |= (u32)h0 << 16; q1[j>>1] |= (u32)h1 << 16; q2[j>>1] |= (u32)h2 << 16; }
        }
        const int c = cq * 64 + i0;
        const size_t chunk = (((size_t)((c >> 5) * 4 + ((c >> 3) & 3))) << 15)
                             + (size_t)bi * 64 + p;
        *(uint4*)(X0 + chunk * 8) = make_uint4(q0[0], q0[1], q0[2], q0[3]);
        *(uint4*)(X1 + chunk * 8) = make_uint4(q1[0], q1[1], q1[2], q1[3]);
        *(uint4*)(X2 + chunk * 8) = make_uint4(q2[0], q2[1], q2[2], q2[3]);
    }
    nxp[cq][p] = s;
    __syncthreads();
    if (t < 64)
        nx_out[bi * 64 + t] = ((nxp[0][t] + nxp[1][t]) + nxp[2][t]) + nxp[3][t];
}

// ---------------------------------------------------------------------------
// prep_e: same split for the codebook -> [kc][kb][code(1024)][8k] + |e|^2
// ---------------------------------------------------------------------------
__global__ __launch_bounds__(256) void k_prep_e(const float* __restrict__ cb,
        u16* __restrict__ E0, u16* __restrict__ E1, u16* __restrict__ E2,
        float* __restrict__ ne_out)
{
    const int t = threadIdx.x;
    const int l32 = t & 31;
    const int code = blockIdx.x * 8 + (t >> 5);
    const float* cp = cb + (size_t)code * 256 + l32 * 8;
    u32 q0[4], q1[4], q2[4];
    float s = 0.f;
#pragma unroll
    for (int j = 0; j < 8; ++j) {
        float v = cp[j];
        s = fmaf(v, v, s);
        u16 h0 = f32_bf16(v);
        float r1 = v - bf16_f32(h0);
        u16 h1 = f32_bf16(r1);
        u16 h2 = f32_bf16(r1 - bf16_f32(h1));
        if ((j & 1) == 0) { q0[j>>1] = h0; q1[j>>1] = h1; q2[j>>1] = h2; }
        else { q0[j>>1] |= (u32)h0 << 16; q1[j>>1] |= (u32)h1 << 16; q2[j>>1] |= (u32)h2 << 16; }
    }
    const size_t chunk = ((size_t)l32 << 10) + code;
    *(uint4*)(E0 + chunk * 8) = make_uint4(q0[0], q0[1], q0[2], q0[3]);
    *(uint4*)(E1 + chunk * 8) = make_uint4(q1[0], q1[1], q1[2], q1[3]);
    *(uint4*)(E2 + chunk * 8) = make_uint4(q2[0], q2[1], q2[2], q2[3]);
#pragma unroll
    for (int off = 16; off > 0; off >>= 1) s += __shfl_xor(s, off);
    if (l32 == 0) ne_out[code] = s;
}

// ---------------------------------------------------------------------------
// MFMA distance-argmin: per block 128 px x 128 codes, BK=32, 4 waves (2x2).
// Round-4 structure:
//   - 32x32x16 MFMA (2382 TF ceiling, half the instr count of 16x16x32)
//   - 3 blocks/CU (launch_bounds(256,3); LDS 51200*3 fits in 160KB)
//   - XCD swizzle, A-dbuf 2-phase pipeline, B direct global->reg (L2)
// A-frag (hw-verified generalization): lane l -> row l%32, k=(l/32)*8+j
// C/D (m74/m101): col=lane&31, row=(reg&3)+8*(reg>>2)+4*(lane>>5)
// ---------------------------------------------------------------------------
__global__ __launch_bounds__(256, 3) void k_mfma_argmin(
        const u16* __restrict__ X0, const u16* __restrict__ X1, const u16* __restrict__ X2,
        const u16* __restrict__ E0, const u16* __restrict__ E1, const u16* __restrict__ E2,
        const float* __restrict__ nx, const float* __restrict__ ne,
        float* __restrict__ partV, int* __restrict__ partI)
{
    __shared__ __align__(16) unsigned char lds[2][24576];   // A dbuf: 3T x 8KB
    __shared__ float redV[2][128];
    __shared__ int   redI[2][128];

    const int t = threadIdx.x;
    const int l = t & 63;
    const int w = t >> 6;

    // XCD-aware bijective swizzle (grid 2048 % 8 == 0)
    const int bi   = blockIdx.x;
    const int xcd  = bi & 7;
    const int slot = bi >> 3;
    const int cT   = slot & 7;
    const int pT   = ((slot >> 3) << 3) | xcd;
    const int px0  = pT << 7;
    const int c0   = cT << 7;
    const int wm = w >> 1, wn = w & 1;
    const int m0 = wm << 6, n0 = wn << 6;    // wave tile 64x64
    const int col = l & 31;                  // 32-row/col fragment index
    const int hi  = l >> 5;                  // k-half selector

    const u16* Xt[3] = {X0, X1, X2};
    const u16* Et[3] = {E0, E1, E2};

    f32x16 acc[2][2];
#pragma unroll
    for (int i = 0; i < 2; ++i)
#pragma unroll
        for (int j = 0; j < 2; ++j)
#pragma unroll
            for (int r = 0; r < 16; ++r) acc[i][j][r] = 0.f;

    // stage A tile (3T x 128px x 32d bf16 = 24KB) for K-step kc into buffer bf
    auto stageA = [&](int kc, int bf) {
#pragma unroll
        for (int T = 0; T < 3; ++T) {
#pragma unroll
            for (int half = 0; half < 2; ++half) {
                const int ci  = half * 256 + w * 64 + l;   // 0..511 chunk id
                const int pxl = ci & 127;
                const int kb  = ci >> 7;
                const u16* sa = Xt[T] + ((((size_t)(kc * 4 + kb)) << 15) + px0 + pxl) * 8;
                __builtin_amdgcn_global_load_lds(
                    (const __attribute__((address_space(1))) void*)sa,
                    (__attribute__((address_space(3))) void*)(&lds[bf][T * 8192 + ci * 16]),
                    16, 0, 0);
            }
        }
    };

    stageA(0, 0);
    __syncthreads();                       // drain prologue stage

    const int TA[6] = {0, 0, 1, 1, 0, 2};
    const int TB[6] = {0, 1, 0, 1, 2, 0};

#pragma unroll
    for (int kc = 0; kc < 8; ++kc) {
        const int bf = kc & 1;
        if (kc < 7) stageA(kc + 1, bf ^ 1);   // overlaps with MFMA below

#pragma unroll
        for (int kf = 0; kf < 2; ++kf) {      // two K=16 steps per kc
            const int kb = kf * 2 + hi;       // chunk-of-8 within the 32-dim step

            // B fragments direct from global (L2-resident, frag-major)
            bf16x8 bq[3][2];
#pragma unroll
            for (int T = 0; T < 3; ++T)
#pragma unroll
                for (int ni = 0; ni < 2; ++ni)
                    bq[T][ni] = *(const bf16x8*)(Et[T]
                        + ((((size_t)(kc * 4 + kb)) << 10) + c0 + n0 + ni * 32 + col) * 8);

            bf16x8 af[3][2];
#pragma unroll
            for (int T = 0; T < 3; ++T)
#pragma unroll
                for (int mi = 0; mi < 2; ++mi)
                    af[T][mi] = *(const bf16x8*)(&lds[bf][T * 8192
                                + (kb * 128 + m0 + mi * 32 + col) * 16]);

#pragma unroll
            for (int tp = 0; tp < 6; ++tp)
#pragma unroll
                for (int mi = 0; mi < 2; ++mi)
#pragma unroll
                    for (int ni = 0; ni < 2; ++ni)
                        acc[mi][ni] = __builtin_amdgcn_mfma_f32_32x32x16_bf16(
                            af[TA[tp]][mi], bq[TB[tp]][ni], acc[mi][ni], 0, 0, 0);
        }

        __syncthreads();                   // drains stage(kc+1), guards dbuf swap
    }

    // ---- epilogue: scores + argmin ----
    float nev[2];
#pragma unroll
    for (int ni = 0; ni < 2; ++ni) nev[ni] = ne[c0 + n0 + ni * 32 + col];
#pragma unroll
    for (int mi = 0; mi < 2; ++mi) {
#pragma unroll
        for (int r = 0; r < 16; ++r) {
            const int pxl = m0 + mi * 32 + (r & 3) + 8 * (r >> 2) + 4 * hi;
            const float nxv = nx[px0 + pxl];
            float best = 3.4e38f; int besti = 0;
#pragma unroll
            for (int ni = 0; ni < 2; ++ni) {
                float sc = (nxv + nev[ni]) - 2.0f * acc[mi][ni][r];
                if (sc < best) { best = sc; besti = c0 + n0 + ni * 32 + col; }
            }
#pragma unroll
            for (int off = 1; off < 32; off <<= 1) {   // reduce within 32-lane group
                float ov = __shfl_xor(best, off);
                int   oi = __shfl_xor(besti, off);
                if (ov < best || (ov == best && oi < besti)) { best = ov; besti = oi; }
            }
            if (col == 0) { redV[wn][pxl] = best; redI[wn][pxl] = besti; }
        }
    }
    __syncthreads();
    if (t < 128) {
        float v0 = redV[0][t]; int i0 = redI[0][t];
        float v1 = redV[1][t]; int i1 = redI[1][t];
        if (v1 < v0 || (v1 == v0 && i1 < i0)) { v0 = v1; i0 = i1; }
        partV[cT * NPIX + px0 + t] = v0;
        partI[cT * NPIX + px0 + t] = i0;
    }
}

// ---------------------------------------------------------------------------
// final ids: lexicographic reduce over the 8 code-tiles
// ---------------------------------------------------------------------------
__global__ __launch_bounds__(256) void k_final_ids(const float* __restrict__ partV,
                                                   const int* __restrict__ partI,
                                                   float* __restrict__ ids_f)
{
    const int px = blockIdx.x * 256 + threadIdx.x;   // grid 128
    float bv = partV[px]; int bi = partI[px];
#pragma unroll
    for (int ct = 1; ct < 8; ++ct) {
        float v = partV[ct * NPIX + px];
        int   i = partI[ct * NPIX + px];
        if (v < bv || (v == bv && i < bi)) { bv = v; bi = i; }
    }
    ids_f[px] = (float)bi;
}

// ===========================================================================
// FALLBACK (round-0 passing path, used if ws too small)
// ===========================================================================
__global__ __launch_bounds__(256) void k_enorm(const float* __restrict__ cb,
                                               float* __restrict__ enorm)
{
    const int tid  = threadIdx.x;
    const int lane = tid & 63;
    const int w    = tid >> 6;
    const int k    = blockIdx.x * 4 + w;
    const float* cp = cb + (size_t)k * DIM;
    float s = 0.f;
#pragma unroll
    for (int t = 0; t < 4; ++t) {
        float v = cp[lane + t * 64];
        s = fmaf(v, v, s);
    }
#pragma unroll
    for (int off = 32; off > 0; off >>= 1) s += __shfl_down(s, off);
    if (lane == 0) enorm[k] = s;
}

__global__ __launch_bounds__(256) void k_argmin(const float* __restrict__ x,
                                                const float* __restrict__ cb,
                                                const float* __restrict__ enorm,
                                                float* __restrict__ out_ids)
{
    __shared__ float xs[32][64];
    __shared__ float cbs[32][68];
    __shared__ float nx_l[64];
    __shared__ float nxp[4][64];
    __shared__ float red_v[64][17];
    __shared__ int   red_i[64][17];

    const int tid  = threadIdx.x;
    const int tx   = tid & 15;
    const int ty   = tid >> 4;
    const int pix0 = blockIdx.x * 64;
    const int b    = pix0 >> 10;
    const int hw0  = pix0 & 1023;

    {
        const int p = tid & 63, q = tid >> 6;
        float s = 0.f;
        const float* xp = x + ((size_t)(b * DIM + q * 64) * 1024) + hw0 + p;
        for (int c = 0; c < 64; ++c) {
            float v = xp[c * 1024];
            s = fmaf(v, v, s);
        }
        nxp[q][p] = s;
        __syncthreads();
        if (tid < 64)
            nx_l[tid] = ((nxp[0][tid] + nxp[1][tid]) + nxp[2][tid]) + nxp[3][tid];
        __syncthreads();
    }

    float nx_r[4];
#pragma unroll
    for (int i = 0; i < 4; ++i) nx_r[i] = nx_l[ty * 4 + i];

    float best_v[4];
    int   best_i[4];
#pragma unroll
    for (int i = 0; i < 4; ++i) { best_v[i] = 3.4e38f; best_i[i] = 0; }

    for (int cc = 0; cc < 16; ++cc) {
        float acc[4][4];
#pragma unroll
        for (int i = 0; i < 4; ++i)
#pragma unroll
            for (int j = 0; j < 4; ++j) acc[i][j] = 0.f;

        for (int kcc = 0; kcc < 8; ++kcc) {
            __syncthreads();
            {
                const int p = tid & 63, k0 = tid >> 6;
                const float* xp = x + ((size_t)(b * DIM + kcc * 32) * 1024) + hw0 + p;
#pragma unroll
                for (int tt = 0; tt < 8; ++tt) {
                    int kk = k0 + tt * 4;
                    xs[kk][p] = xp[kk * 1024];
                }
            }
            {
                const int kk = tid & 31, r0 = tid >> 5;
                const float* cp = cb + (size_t)(cc * 64) * DIM + kcc * 32 + kk;
#pragma unroll
                for (int tt = 0; tt < 8; ++tt) {
                    int r = r0 + tt * 8;
                    cbs[kk][r] = cp[r * DIM];
                }
            }
            __syncthreads();
#pragma unroll
            for (int kk = 0; kk < 32; ++kk) {
                float4 A = *(const float4*)&xs[kk][ty * 4];
                float4 B = *(const float4*)&cbs[kk][tx * 4];
                float a[4] = {A.x, A.y, A.z, A.w};
                float bb[4] = {B.x, B.y, B.z, B.w};
#pragma unroll
                for (int i = 0; i < 4; ++i)
#pragma unroll
                    for (int j = 0; j < 4; ++j)
                        acc[i][j] = fmaf(a[i], bb[j], acc[i][j]);
            }
        }

#pragma unroll
        for (int j = 0; j < 4; ++j) {
            const int code = cc * 64 + tx * 4 + j;
            const float nee = enorm[code];
#pragma unroll
            for (int i = 0; i < 4; ++i) {
                float s = (nx_r[i] + nee) - 2.0f * acc[i][j];
                if (s < best_v[i]) { best_v[i] = s; best_i[i] = code; }
            }
        }
    }

#pragma unroll
    for (int i = 0; i < 4; ++i) {
        red_v[ty * 4 + i][tx] = best_v[i];
        red_i[ty * 4 + i][tx] = best_i[i];
    }
    __syncthreads();
    if (tid < 64) {
        float bv = red_v[tid][0];
        int   bi = red_i[tid][0];
#pragma unroll
        for (int tt = 1; tt < 16; ++tt) {
            float v = red_v[tid][tt];
            int   idx = red_i[tid][tt];
            if (v < bv || (v == bv && idx < bi)) { bv = v; bi = idx; }
        }
        out_ids[pix0 + tid] = (float)bi;
    }
}

// ===========================================================================
// shared epilogue kernels
// ===========================================================================
__global__ __launch_bounds__(256) void k_outputs(const float* __restrict__ x,
                                                 const float* __restrict__ cb,
                                                 const float* __restrict__ ids_f,
                                                 float* __restrict__ out_emb,
                                                 float* __restrict__ partials)
{
    const int tid = threadIdx.x;
    const int gid = blockIdx.x * 256 + tid;
    float s = 0.f;
#pragma unroll 4
    for (int it = 0; it < 32; ++it) {
        int i  = gid + it * 262144;
        int c  = (i >> 10) & 255;
        int bb = i >> 18;
        int hw = i & 1023;
        int n  = (bb << 10) + hw;
        int id = (int)ids_f[n];
        float e  = cb[id * DIM + c];
        float xv = x[i];
        out_emb[i] = xv + (e - xv);
        float d = xv - e;
        s = fmaf(d, d, s);
    }
    __shared__ float sm[256];
    sm[tid] = s;
    __syncthreads();
    for (int off = 128; off > 0; off >>= 1) {
        if (tid < off) sm[tid] += sm[tid + off];
        __syncthreads();
    }
    if (tid == 0) partials[blockIdx.x] = sm[0];
}

__global__ __launch_bounds__(256) void k_finalize(const float* __restrict__ partials,
                                                  float* __restrict__ out_loss)
{
    __shared__ float sm[256];
    const int tid = threadIdx.x;
    float s = ((partials[tid] + partials[tid + 256]) + partials[tid + 512])
              + partials[tid + 768];
    sm[tid] = s;
    __syncthreads();
    for (int off = 128; off > 0; off >>= 1) {
        if (tid < off) sm[tid] += sm[tid + off];
        __syncthreads();
    }
    if (tid == 0) {
        float m = sm[0] / (float)NELEM;
        out_loss[0] = m + 0.25f * m;
    }
}

// ===========================================================================
extern "C" void kernel_launch(void* const* d_in, const int* in_sizes, int n_in,
                              void* d_out, int out_size, void* d_ws, size_t ws_size,
                              hipStream_t stream)
{
    const float* x  = (const float*)d_in[0];   // (32,256,32,32)
    const float* cb = (const float*)d_in[1];   // (1024,256)
    float* out   = (float*)d_out;
    float* ids_f = out;                        // 32768
    float* emb   = out + NPIX;                 // 8388608
    float* loss  = out + NPIX + NELEM;         // 1

    char* wsb = (char*)d_ws;
    const size_t NEED = 54145024ull;           // 48M X' + 1.5M E' + aux
    if (ws_size >= NEED) {
        u16*   X0 = (u16*)(wsb);
        u16*   X1 = (u16*)(wsb + 16777216);
        u16*   X2 = (u16*)(wsb + 33554432);
        u16*   E0 = (u16*)(wsb + 50331648);
        u16*   E1 = (u16*)(wsb + 50855936);
        u16*   E2 = (u16*)(wsb + 51380224);
        float* nx = (float*)(wsb + 51904512);
        float* ne = (float*)(wsb + 52035584);
        float* pV = (float*)(wsb + 52039680);
        int*   pI = (int*)  (wsb + 53088256);
        float* lp = (float*)(wsb + 54136832);
        k_prep_x    <<<512,  256, 0, stream>>>(x, X0, X1, X2, nx);
        k_prep_e    <<<128,  256, 0, stream>>>(cb, E0, E1, E2, ne);
        k_mfma_argmin<<<2048, 256, 0, stream>>>(X0, X1, X2, E0, E1, E2, nx, ne, pV, pI);
        k_final_ids <<<128,  256, 0, stream>>>(pV, pI, ids_f);
        k_outputs   <<<1024, 256, 0, stream>>>(x, cb, ids_f, emb, lp);
        k_finalize  <<<1,    256, 0, stream>>>(lp, loss);
    } else {
        float* partials = (float*)wsb;         // 1024 floats
        float* enorm    = partials + 1024;     // 1024 floats
        k_enorm   <<<256,  256, 0, stream>>>(cb, enorm);
        k_argmin  <<<512,  256, 0, stream>>>(x, cb, enorm, ids_f);
        k_outputs <<<1024, 256, 0, stream>>>(x, cb, ids_f, emb, partials);
        k_finalize<<<1,    256, 0, stream>>>(partials, loss);
    }
}

// Round 5
// 152.890 us; speedup vs baseline: 1.2156x; 1.2156x over previous
//
#include <hip/hip_runtime.h>

#define NUM_EMB 1024
#define DIM     256
#define NPIX    32768      // 32 * 32 * 32
#define NELEM   8388608    // 32 * 256 * 32 * 32

typedef unsigned short u16;
typedef unsigned int   u32;
typedef __attribute__((ext_vector_type(8))) short bf16x8;
typedef __attribute__((ext_vector_type(4))) float f32x4;

__device__ __forceinline__ u16 f32_bf16(float f) {
    u32 u = __float_as_uint(f);
    u += 0x7fffu + ((u >> 16) & 1u);          // round-to-nearest-even
    return (u16)(u >> 16);
}
__device__ __forceinline__ float bf16_f32(u16 h) {
    return __uint_as_float((u32)h << 16);
}

// ===========================================================================
// MFMA path
// ===========================================================================

// ---------------------------------------------------------------------------
// prep_x: split x (f32, (32,256,32,32)) into 3 bf16 arrays in frag-major
// layout [kc(8)][kb(4)][px(32768)][8k] and compute |x|^2 per pixel.
// ---------------------------------------------------------------------------
__global__ __launch_bounds__(256) void k_prep_x(const float* __restrict__ x,
        u16* __restrict__ X0, u16* __restrict__ X1, u16* __restrict__ X2,
        float* __restrict__ nx_out)
{
    __shared__ float nxp[4][64];
    const int t  = threadIdx.x;
    const int p  = t & 63;
    const int cq = t >> 6;
    const int bi = blockIdx.x;            // 512
    const int b  = bi >> 4;
    const int hw = ((bi & 15) << 6) + p;
    const float* xp = x + (((size_t)(b * 256 + cq * 64)) << 10) + hw;
    float s = 0.f;
    for (int i0 = 0; i0 < 64; i0 += 8) {
        u32 q0[4], q1[4], q2[4];
#pragma unroll
        for (int j = 0; j < 8; ++j) {
            float v = xp[(size_t)(i0 + j) << 10];
            s = fmaf(v, v, s);
            u16 h0 = f32_bf16(v);
            float r1 = v - bf16_f32(h0);          // exact (Sterbenz)
            u16 h1 = f32_bf16(r1);
            u16 h2 = f32_bf16(r1 - bf16_f32(h1)); // residual <= 2^-27 |v|
            if ((j & 1) == 0) { q0[j>>1] = h0; q1[j>>1] = h1; q2[j>>1] = h2; }
            else { q0[j>>1] |= (u32)h0 << 16; q1[j>>1] |= (u32)h1 << 16; q2[j>>1] |= (u32)h2 << 16; }
        }
        const int c = cq * 64 + i0;
        const size_t chunk = (((size_t)((c >> 5) * 4 + ((c >> 3) & 3))) << 15)
                             + (size_t)bi * 64 + p;
        *(uint4*)(X0 + chunk * 8) = make_uint4(q0[0], q0[1], q0[2], q0[3]);
        *(uint4*)(X1 + chunk * 8) = make_uint4(q1[0], q1[1], q1[2], q1[3]);
        *(uint4*)(X2 + chunk * 8) = make_uint4(q2[0], q2[1], q2[2], q2[3]);
    }
    nxp[cq][p] = s;
    __syncthreads();
    if (t < 64)
        nx_out[bi * 64 + t] = ((nxp[0][t] + nxp[1][t]) + nxp[2][t]) + nxp[3][t];
}

// ---------------------------------------------------------------------------
// prep_e: same split for the codebook -> [kc][kb][code(1024)][8k] + |e|^2
// ---------------------------------------------------------------------------
__global__ __launch_bounds__(256) void k_prep_e(const float* __restrict__ cb,
        u16* __restrict__ E0, u16* __restrict__ E1, u16* __restrict__ E2,
        float* __restrict__ ne_out)
{
    const int t = threadIdx.x;
    const int l32 = t & 31;
    const int code = blockIdx.x * 8 + (t >> 5);
    const float* cp = cb + (size_t)code * 256 + l32 * 8;
    u32 q0[4], q1[4], q2[4];
    float s = 0.f;
#pragma unroll
    for (int j = 0; j < 8; ++j) {
        float v = cp[j];
        s = fmaf(v, v, s);
        u16 h0 = f32_bf16(v);
        float r1 = v - bf16_f32(h0);
        u16 h1 = f32_bf16(r1);
        u16 h2 = f32_bf16(r1 - bf16_f32(h1));
        if ((j & 1) == 0) { q0[j>>1] = h0; q1[j>>1] = h1; q2[j>>1] = h2; }
        else { q0[j>>1] |= (u32)h0 << 16; q1[j>>1] |= (u32)h1 << 16; q2[j>>1] |= (u32)h2 << 16; }
    }
    const size_t chunk = ((size_t)l32 << 10) + code;
    *(uint4*)(E0 + chunk * 8) = make_uint4(q0[0], q0[1], q0[2], q0[3]);
    *(uint4*)(E1 + chunk * 8) = make_uint4(q1[0], q1[1], q1[2], q1[3]);
    *(uint4*)(E2 + chunk * 8) = make_uint4(q2[0], q2[1], q2[2], q2[3]);
#pragma unroll
    for (int off = 16; off > 0; off >>= 1) s += __shfl_xor(s, off);
    if (l32 == 0) ne_out[code] = s;
}

// ---------------------------------------------------------------------------
// MFMA distance-argmin: per block 128 px x 128 codes, BK=32, 4 waves (2x2).
// Round-5 structure:
//   - 16x16x32 MFMA (16 independent acc chains — round-4 post-mortem)
//   - NO LDS, NO barriers in the K-loop: both A (X') and B (E') fragments
//     load global->register. Frag-major layout => 16-lane 256B segments.
//     XCD swizzle keeps both panels L2-resident (31MB FETCH, round 3).
//   - fully unrolled K-loop: compiler hoists kc+1 loads over kc MFMAs.
// Math order identical to rounds 2/3 -> bit-identical scores.
// ---------------------------------------------------------------------------
__global__ __launch_bounds__(256, 2) void k_mfma_argmin(
        const u16* __restrict__ X0, const u16* __restrict__ X1, const u16* __restrict__ X2,
        const u16* __restrict__ E0, const u16* __restrict__ E1, const u16* __restrict__ E2,
        const float* __restrict__ nx, const float* __restrict__ ne,
        float* __restrict__ partV, int* __restrict__ partI)
{
    __shared__ float redV[2][128];
    __shared__ int   redI[2][128];

    const int t = threadIdx.x;
    const int l = t & 63;
    const int w = t >> 6;

    // XCD-aware bijective swizzle (grid 2048 % 8 == 0)
    const int bi   = blockIdx.x;
    const int xcd  = bi & 7;
    const int slot = bi >> 3;
    const int cT   = slot & 7;
    const int pT   = ((slot >> 3) << 3) | xcd;
    const int px0  = pT << 7;
    const int c0   = cT << 7;
    const int wm = w >> 1, wn = w & 1;
    const int m0 = wm << 6, n0 = wn << 6;
    const int kbl = l >> 4;
    const int il  = l & 15;

    f32x4 acc[4][4];
#pragma unroll
    for (int i = 0; i < 4; ++i)
#pragma unroll
        for (int j = 0; j < 4; ++j) acc[i][j] = (f32x4){0.f, 0.f, 0.f, 0.f};

    // per-lane base pointers (elements):
    //  A(T,mi,kc) = Xt[T] + kbl*262144 + (px0+m0+il)*8 + kc*1048576 + mi*128
    //  B(T,ni,kc) = Et[T] + kbl*8192   + (c0+n0+il)*8  + kc*32768   + ni*128
    const size_t aoff = (size_t)kbl * 262144 + (size_t)(px0 + m0 + il) * 8;
    const size_t boff = (size_t)kbl * 8192   + (size_t)(c0  + n0 + il) * 8;
    const u16* pA[3] = {X0 + aoff, X1 + aoff, X2 + aoff};
    const u16* pB[3] = {E0 + boff, E1 + boff, E2 + boff};

    const int TA[6] = {0, 0, 1, 1, 0, 2};
    const int TB[6] = {0, 1, 0, 1, 2, 0};

#pragma unroll
    for (int kc = 0; kc < 8; ++kc) {
        bf16x8 af[3][4], bq[3][4];
#pragma unroll
        for (int T = 0; T < 3; ++T) {
#pragma unroll
            for (int mi = 0; mi < 4; ++mi)
                af[T][mi] = *(const bf16x8*)(pA[T] + (size_t)kc * 1048576 + mi * 128);
#pragma unroll
            for (int ni = 0; ni < 4; ++ni)
                bq[T][ni] = *(const bf16x8*)(pB[T] + (size_t)kc * 32768 + ni * 128);
        }
#pragma unroll
        for (int tp = 0; tp < 6; ++tp)
#pragma unroll
            for (int mi = 0; mi < 4; ++mi)
#pragma unroll
                for (int ni = 0; ni < 4; ++ni)
                    acc[mi][ni] = __builtin_amdgcn_mfma_f32_16x16x32_bf16(
                        af[TA[tp]][mi], bq[TB[tp]][ni], acc[mi][ni], 0, 0, 0);
    }

    // ---- epilogue: scores + argmin (C/D map: col=lane&15, row=(lane>>4)*4+r) ----
    const int g = l >> 4, col = l & 15;
    float nev[4];
#pragma unroll
    for (int ni = 0; ni < 4; ++ni) nev[ni] = ne[c0 + n0 + ni * 16 + col];
#pragma unroll
    for (int mi = 0; mi < 4; ++mi) {
#pragma unroll
        for (int r = 0; r < 4; ++r) {
            const int pxl = m0 + mi * 16 + g * 4 + r;
            const float nxv = nx[px0 + pxl];
            float best = 3.4e38f; int besti = 0;
#pragma unroll
            for (int ni = 0; ni < 4; ++ni) {
                float sc = (nxv + nev[ni]) - 2.0f * acc[mi][ni][r];
                if (sc < best) { best = sc; besti = c0 + n0 + ni * 16 + col; }
            }
#pragma unroll
            for (int off = 1; off < 16; off <<= 1) {
                float ov = __shfl_xor(best, off);
                int   oi = __shfl_xor(besti, off);
                if (ov < best || (ov == best && oi < besti)) { best = ov; besti = oi; }
            }
            if (col == 0) { redV[wn][pxl] = best; redI[wn][pxl] = besti; }
        }
    }
    __syncthreads();
    if (t < 128) {
        float v0 = redV[0][t]; int i0 = redI[0][t];
        float v1 = redV[1][t]; int i1 = redI[1][t];
        if (v1 < v0 || (v1 == v0 && i1 < i0)) { v0 = v1; i0 = i1; }
        partV[cT * NPIX + px0 + t] = v0;
        partI[cT * NPIX + px0 + t] = i0;
    }
}

// ---------------------------------------------------------------------------
// final ids: lexicographic reduce over the 8 code-tiles
// ---------------------------------------------------------------------------
__global__ __launch_bounds__(256) void k_final_ids(const float* __restrict__ partV,
                                                   const int* __restrict__ partI,
                                                   float* __restrict__ ids_f)
{
    const int px = blockIdx.x * 256 + threadIdx.x;   // grid 128
    float bv = partV[px]; int bi = partI[px];
#pragma unroll
    for (int ct = 1; ct < 8; ++ct) {
        float v = partV[ct * NPIX + px];
        int   i = partI[ct * NPIX + px];
        if (v < bv || (v == bv && i < bi)) { bv = v; bi = i; }
    }
    ids_f[px] = (float)bi;
}

// ===========================================================================
// FALLBACK (round-0 passing path, used if ws too small)
// ===========================================================================
__global__ __launch_bounds__(256) void k_enorm(const float* __restrict__ cb,
                                               float* __restrict__ enorm)
{
    const int tid  = threadIdx.x;
    const int lane = tid & 63;
    const int w    = tid >> 6;
    const int k    = blockIdx.x * 4 + w;
    const float* cp = cb + (size_t)k * DIM;
    float s = 0.f;
#pragma unroll
    for (int t = 0; t < 4; ++t) {
        float v = cp[lane + t * 64];
        s = fmaf(v, v, s);
    }
#pragma unroll
    for (int off = 32; off > 0; off >>= 1) s += __shfl_down(s, off);
    if (lane == 0) enorm[k] = s;
}

__global__ __launch_bounds__(256) void k_argmin(const float* __restrict__ x,
                                                const float* __restrict__ cb,
                                                const float* __restrict__ enorm,
                                                float* __restrict__ out_ids)
{
    __shared__ float xs[32][64];
    __shared__ float cbs[32][68];
    __shared__ float nx_l[64];
    __shared__ float nxp[4][64];
    __shared__ float red_v[64][17];
    __shared__ int   red_i[64][17];

    const int tid  = threadIdx.x;
    const int tx   = tid & 15;
    const int ty   = tid >> 4;
    const int pix0 = blockIdx.x * 64;
    const int b    = pix0 >> 10;
    const int hw0  = pix0 & 1023;

    {
        const int p = tid & 63, q = tid >> 6;
        float s = 0.f;
        const float* xp = x + ((size_t)(b * DIM + q * 64) * 1024) + hw0 + p;
        for (int c = 0; c < 64; ++c) {
            float v = xp[c * 1024];
            s = fmaf(v, v, s);
        }
        nxp[q][p] = s;
        __syncthreads();
        if (tid < 64)
            nx_l[tid] = ((nxp[0][tid] + nxp[1][tid]) + nxp[2][tid]) + nxp[3][tid];
        __syncthreads();
    }

    float nx_r[4];
#pragma unroll
    for (int i = 0; i < 4; ++i) nx_r[i] = nx_l[ty * 4 + i];

    float best_v[4];
    int   best_i[4];
#pragma unroll
    for (int i = 0; i < 4; ++i) { best_v[i] = 3.4e38f; best_i[i] = 0; }

    for (int cc = 0; cc < 16; ++cc) {
        float acc[4][4];
#pragma unroll
        for (int i = 0; i < 4; ++i)
#pragma unroll
            for (int j = 0; j < 4; ++j) acc[i][j] = 0.f;

        for (int kcc = 0; kcc < 8; ++kcc) {
            __syncthreads();
            {
                const int p = tid & 63, k0 = tid >> 6;
                const float* xp = x + ((size_t)(b * DIM + kcc * 32) * 1024) + hw0 + p;
#pragma unroll
                for (int tt = 0; tt < 8; ++tt) {
                    int kk = k0 + tt * 4;
                    xs[kk][p] = xp[kk * 1024];
                }
            }
            {
                const int kk = tid & 31, r0 = tid >> 5;
                const float* cp = cb + (size_t)(cc * 64) * DIM + kcc * 32 + kk;
#pragma unroll
                for (int tt = 0; tt < 8; ++tt) {
                    int r = r0 + tt * 8;
                    cbs[kk][r] = cp[r * DIM];
                }
            }
            __syncthreads();
#pragma unroll
            for (int kk = 0; kk < 32; ++kk) {
                float4 A = *(const float4*)&xs[kk][ty * 4];
                float4 B = *(const float4*)&cbs[kk][tx * 4];
                float a[4] = {A.x, A.y, A.z, A.w};
                float bb[4] = {B.x, B.y, B.z, B.w};
#pragma unroll
                for (int i = 0; i < 4; ++i)
#pragma unroll
                    for (int j = 0; j < 4; ++j)
                        acc[i][j] = fmaf(a[i], bb[j], acc[i][j]);
            }
        }

#pragma unroll
        for (int j = 0; j < 4; ++j) {
            const int code = cc * 64 + tx * 4 + j;
            const float nee = enorm[code];
#pragma unroll
            for (int i = 0; i < 4; ++i) {
                float s = (nx_r[i] + nee) - 2.0f * acc[i][j];
                if (s < best_v[i]) { best_v[i] = s; best_i[i] = code; }
            }
        }
    }

#pragma unroll
    for (int i = 0; i < 4; ++i) {
        red_v[ty * 4 + i][tx] = best_v[i];
        red_i[ty * 4 + i][tx] = best_i[i];
    }
    __syncthreads();
    if (tid < 64) {
        float bv = red_v[tid][0];
        int   bi = red_i[tid][0];
#pragma unroll
        for (int tt = 1; tt < 16; ++tt) {
            float v = red_v[tid][tt];
            int   idx = red_i[tid][tt];
            if (v < bv || (v == bv && idx < bi)) { bv = v; bi = idx; }
        }
        out_ids[pix0 + tid] = (float)bi;
    }
}

// ===========================================================================
// shared epilogue kernels
// ===========================================================================
__global__ __launch_bounds__(256) void k_outputs(const float* __restrict__ x,
                                                 const float* __restrict__ cb,
                                                 const float* __restrict__ ids_f,
                                                 float* __restrict__ out_emb,
                                                 float* __restrict__ partials)
{
    const int tid = threadIdx.x;
    const int gid = blockIdx.x * 256 + tid;
    float s = 0.f;
#pragma unroll 4
    for (int it = 0; it < 32; ++it) {
        int i  = gid + it * 262144;
        int c  = (i >> 10) & 255;
        int bb = i >> 18;
        int hw = i & 1023;
        int n  = (bb << 10) + hw;
        int id = (int)ids_f[n];
        float e  = cb[id * DIM + c];
        float xv = x[i];
        out_emb[i] = xv + (e - xv);
        float d = xv - e;
        s = fmaf(d, d, s);
    }
    __shared__ float sm[256];
    sm[tid] = s;
    __syncthreads();
    for (int off = 128; off > 0; off >>= 1) {
        if (tid < off) sm[tid] += sm[tid + off];
        __syncthreads();
    }
    if (tid == 0) partials[blockIdx.x] = sm[0];
}

__global__ __launch_bounds__(256) void k_finalize(const float* __restrict__ partials,
                                                  float* __restrict__ out_loss)
{
    __shared__ float sm[256];
    const int tid = threadIdx.x;
    float s = ((partials[tid] + partials[tid + 256]) + partials[tid + 512])
              + partials[tid + 768];
    sm[tid] = s;
    __syncthreads();
    for (int off = 128; off > 0; off >>= 1) {
        if (tid < off) sm[tid] += sm[tid + off];
        __syncthreads();
    }
    if (tid == 0) {
        float m = sm[0] / (float)NELEM;
        out_loss[0] = m + 0.25f * m;
    }
}

// ===========================================================================
extern "C" void kernel_launch(void* const* d_in, const int* in_sizes, int n_in,
                              void* d_out, int out_size, void* d_ws, size_t ws_size,
                              hipStream_t stream)
{
    const float* x  = (const float*)d_in[0];   // (32,256,32,32)
    const float* cb = (const float*)d_in[1];   // (1024,256)
    float* out   = (float*)d_out;
    float* ids_f = out;                        // 32768
    float* emb   = out + NPIX;                 // 8388608
    float* loss  = out + NPIX + NELEM;         // 1

    char* wsb = (char*)d_ws;
    const size_t NEED = 54145024ull;           // 48M X' + 1.5M E' + aux
    if (ws_size >= NEED) {
        u16*   X0 = (u16*)(wsb);
        u16*   X1 = (u16*)(wsb + 16777216);
        u16*   X2 = (u16*)(wsb + 33554432);
        u16*   E0 = (u16*)(wsb + 50331648);
        u16*   E1 = (u16*)(wsb + 50855936);
        u16*   E2 = (u16*)(wsb + 51380224);
        float* nx = (float*)(wsb + 51904512);
        float* ne = (float*)(wsb + 52035584);
        float* pV = (float*)(wsb + 52039680);
        int*   pI = (int*)  (wsb + 53088256);
        float* lp = (float*)(wsb + 54136832);
        k_prep_x    <<<512,  256, 0, stream>>>(x, X0, X1, X2, nx);
        k_prep_e    <<<128,  256, 0, stream>>>(cb, E0, E1, E2, ne);
        k_mfma_argmin<<<2048, 256, 0, stream>>>(X0, X1, X2, E0, E1, E2, nx, ne, pV, pI);
        k_final_ids <<<128,  256, 0, stream>>>(pV, pI, ids_f);
        k_outputs   <<<1024, 256, 0, stream>>>(x, cb, ids_f, emb, lp);
        k_finalize  <<<1,    256, 0, stream>>>(lp, loss);
    } else {
        float* partials = (float*)wsb;         // 1024 floats
        float* enorm    = partials + 1024;     // 1024 floats
        k_enorm   <<<256,  256, 0, stream>>>(cb, enorm);
        k_argmin  <<<512,  256, 0, stream>>>(x, cb, enorm, ids_f);
        k_outputs <<<1024, 256, 0, stream>>>(x, cb, ids_f, emb, partials);
        k_finalize<<<1,    256, 0, stream>>>(partials, loss);
    }
}

// Round 6
// 143.454 us; speedup vs baseline: 1.2955x; 1.0658x over previous
//
#include <hip/hip_runtime.h>

#define NUM_EMB 1024
#define DIM     256
#define NPIX    32768      // 32 * 32 * 32
#define NELEM   8388608    // 32 * 256 * 32 * 32

typedef unsigned short u16;
typedef unsigned int   u32;
typedef __attribute__((ext_vector_type(8))) _Float16 f16x8;
typedef __attribute__((ext_vector_type(4))) float f32x4;

__device__ __forceinline__ u16 f32_f16(float f) {
    _Float16 h = (_Float16)f;                  // v_cvt_f16_f32, RN-even
    return __builtin_bit_cast(u16, h);
}
__device__ __forceinline__ float f16_f32(u16 b) {
    return (float)__builtin_bit_cast(_Float16, b);
}

// ===========================================================================
// MFMA path — f16 2-term split, 2 scale groups, 3 MFMA term-pairs.
//   x = 4*(Xa + 2^-10*Xb + eps), e = 2^-11*(Ea + 2^-10*Eb + eps)
//   2*x*e = 2^-8 * [S_aa + 2^-10*(S_ab + S_ba)]   (S_bb dropped, ~5e-9)
// All stored f16 values are normal-range (rescaled residuals) — no DAZ risk.
// ===========================================================================

// ---------------------------------------------------------------------------
// prep_x: split x into Xa,Xb f16 arrays, frag-major [kc8][kb4][px][8k];
// |x|^2 per pixel (fmaf chain IDENTICAL to passing rounds).
// ---------------------------------------------------------------------------
__global__ __launch_bounds__(256) void k_prep_x(const float* __restrict__ x,
        u16* __restrict__ Xa, u16* __restrict__ Xb,
        float* __restrict__ nx_out)
{
    __shared__ float nxp[4][64];
    const int t  = threadIdx.x;
    const int p  = t & 63;
    const int cq = t >> 6;
    const int bi = blockIdx.x;            // 512
    const int b  = bi >> 4;
    const int hw = ((bi & 15) << 6) + p;
    const float* xp = x + (((size_t)(b * 256 + cq * 64)) << 10) + hw;
    float s = 0.f;
    for (int i0 = 0; i0 < 64; i0 += 8) {
        u32 qa[4], qb[4];
#pragma unroll
        for (int j = 0; j < 8; ++j) {
            float v = xp[(size_t)(i0 + j) << 10];
            s = fmaf(v, v, s);
            float va = v * 0.25f;                  // exact
            u16 ha = f32_f16(va);
            float rb = (va - f16_f32(ha)) * 1024.0f;   // exact (Sterbenz + pow2)
            u16 hb = f32_f16(rb);
            if ((j & 1) == 0) { qa[j>>1] = ha; qb[j>>1] = hb; }
            else { qa[j>>1] |= (u32)ha << 16; qb[j>>1] |= (u32)hb << 16; }
        }
        const int c = cq * 64 + i0;
        const size_t chunk = (((size_t)((c >> 5) * 4 + ((c >> 3) & 3))) << 15)
                             + (size_t)bi * 64 + p;
        *(uint4*)(Xa + chunk * 8) = make_uint4(qa[0], qa[1], qa[2], qa[3]);
        *(uint4*)(Xb + chunk * 8) = make_uint4(qb[0], qb[1], qb[2], qb[3]);
    }
    nxp[cq][p] = s;
    __syncthreads();
    if (t < 64)
        nx_out[bi * 64 + t] = ((nxp[0][t] + nxp[1][t]) + nxp[2][t]) + nxp[3][t];
}

// ---------------------------------------------------------------------------
// prep_e: same split for codebook -> [kc][kb][code(1024)][8k] + |e|^2
// ---------------------------------------------------------------------------
__global__ __launch_bounds__(256) void k_prep_e(const float* __restrict__ cb,
        u16* __restrict__ Ea, u16* __restrict__ Eb,
        float* __restrict__ ne_out)
{
    const int t = threadIdx.x;
    const int l32 = t & 31;
    const int code = blockIdx.x * 8 + (t >> 5);
    const float* cp = cb + (size_t)code * 256 + l32 * 8;
    u32 qa[4], qb[4];
    float s = 0.f;
#pragma unroll
    for (int j = 0; j < 8; ++j) {
        float v = cp[j];
        s = fmaf(v, v, s);
        float va = v * 2048.0f;                    // exact
        u16 ha = f32_f16(va);
        float rb = (va - f16_f32(ha)) * 1024.0f;   // exact
        u16 hb = f32_f16(rb);
        if ((j & 1) == 0) { qa[j>>1] = ha; qb[j>>1] = hb; }
        else { qa[j>>1] |= (u32)ha << 16; qb[j>>1] |= (u32)hb << 16; }
    }
    const size_t chunk = ((size_t)l32 << 10) + code;
    *(uint4*)(Ea + chunk * 8) = make_uint4(qa[0], qa[1], qa[2], qa[3]);
    *(uint4*)(Eb + chunk * 8) = make_uint4(qb[0], qb[1], qb[2], qb[3]);
#pragma unroll
    for (int off = 16; off > 0; off >>= 1) s += __shfl_xor(s, off);
    if (l32 == 0) ne_out[code] = s;
}

// ---------------------------------------------------------------------------
// MFMA distance-argmin: 128 px x 128 codes per block, 4 waves (2x2),
// round-5 no-LDS structure, f16 3-pair formulation:
//   acc1 += Xa*Ea ;  acc2 += Xb*Ea ;  acc2 += Xa*Eb
// score = fl(fl(nx+ne) - fl( fmaf(acc2,2^-10,acc1) ) * 2^-8 )
// ---------------------------------------------------------------------------
__global__ __launch_bounds__(256, 2) void k_mfma_argmin(
        const u16* __restrict__ XA, const u16* __restrict__ XB,
        const u16* __restrict__ EA, const u16* __restrict__ EB,
        const float* __restrict__ nx, const float* __restrict__ ne,
        float* __restrict__ partV, int* __restrict__ partI)
{
    __shared__ float redV[2][128];
    __shared__ int   redI[2][128];

    const int t = threadIdx.x;
    const int l = t & 63;
    const int w = t >> 6;

    // XCD-aware bijective swizzle (grid 2048 % 8 == 0)
    const int bi   = blockIdx.x;
    const int xcd  = bi & 7;
    const int slot = bi >> 3;
    const int cT   = slot & 7;
    const int pT   = ((slot >> 3) << 3) | xcd;
    const int px0  = pT << 7;
    const int c0   = cT << 7;
    const int wm = w >> 1, wn = w & 1;
    const int m0 = wm << 6, n0 = wn << 6;
    const int kbl = l >> 4;
    const int il  = l & 15;

    f32x4 acc1[4][4], acc2[4][4];
#pragma unroll
    for (int i = 0; i < 4; ++i)
#pragma unroll
        for (int j = 0; j < 4; ++j) {
            acc1[i][j] = (f32x4){0.f, 0.f, 0.f, 0.f};
            acc2[i][j] = (f32x4){0.f, 0.f, 0.f, 0.f};
        }

    const size_t aoff = (size_t)kbl * 262144 + (size_t)(px0 + m0 + il) * 8;
    const size_t boff = (size_t)kbl * 8192   + (size_t)(c0  + n0 + il) * 8;
    const u16* pA[2] = {XA + aoff, XB + aoff};
    const u16* pB[2] = {EA + boff, EB + boff};

#pragma unroll
    for (int kc = 0; kc < 8; ++kc) {
        f16x8 afa[4], afb[4], bqa[4], bqb[4];
#pragma unroll
        for (int mi = 0; mi < 4; ++mi) {
            afa[mi] = *(const f16x8*)(pA[0] + (size_t)kc * 1048576 + mi * 128);
            afb[mi] = *(const f16x8*)(pA[1] + (size_t)kc * 1048576 + mi * 128);
        }
#pragma unroll
        for (int ni = 0; ni < 4; ++ni) {
            bqa[ni] = *(const f16x8*)(pB[0] + (size_t)kc * 32768 + ni * 128);
            bqb[ni] = *(const f16x8*)(pB[1] + (size_t)kc * 32768 + ni * 128);
        }
#pragma unroll
        for (int mi = 0; mi < 4; ++mi)
#pragma unroll
            for (int ni = 0; ni < 4; ++ni) {
                acc1[mi][ni] = __builtin_amdgcn_mfma_f32_16x16x32_f16(
                    afa[mi], bqa[ni], acc1[mi][ni], 0, 0, 0);
                acc2[mi][ni] = __builtin_amdgcn_mfma_f32_16x16x32_f16(
                    afb[mi], bqa[ni], acc2[mi][ni], 0, 0, 0);
                acc2[mi][ni] = __builtin_amdgcn_mfma_f32_16x16x32_f16(
                    afa[mi], bqb[ni], acc2[mi][ni], 0, 0, 0);
            }
    }

    // ---- epilogue: scores + argmin (C/D map: col=lane&15, row=(lane>>4)*4+r) ----
    const int g = l >> 4, col = l & 15;
    float nev[4];
#pragma unroll
    for (int ni = 0; ni < 4; ++ni) nev[ni] = ne[c0 + n0 + ni * 16 + col];
#pragma unroll
    for (int mi = 0; mi < 4; ++mi) {
#pragma unroll
        for (int r = 0; r < 4; ++r) {
            const int pxl = m0 + mi * 16 + g * 4 + r;
            const float nxv = nx[px0 + pxl];
            float best = 3.4e38f; int besti = 0;
#pragma unroll
            for (int ni = 0; ni < 4; ++ni) {
                float tt = fmaf(acc2[mi][ni][r], 9.765625e-04f, acc1[mi][ni][r]);
                float sc = (nxv + nev[ni]) - tt * 3.90625e-03f;  // pow2 scale exact
                if (sc < best) { best = sc; besti = c0 + n0 + ni * 16 + col; }
            }
#pragma unroll
            for (int off = 1; off < 16; off <<= 1) {
                float ov = __shfl_xor(best, off);
                int   oi = __shfl_xor(besti, off);
                if (ov < best || (ov == best && oi < besti)) { best = ov; besti = oi; }
            }
            if (col == 0) { redV[wn][pxl] = best; redI[wn][pxl] = besti; }
        }
    }
    __syncthreads();
    if (t < 128) {
        float v0 = redV[0][t]; int i0 = redI[0][t];
        float v1 = redV[1][t]; int i1 = redI[1][t];
        if (v1 < v0 || (v1 == v0 && i1 < i0)) { v0 = v1; i0 = i1; }
        partV[cT * NPIX + px0 + t] = v0;
        partI[cT * NPIX + px0 + t] = i0;
    }
}

// ---------------------------------------------------------------------------
// final ids: lexicographic reduce over the 8 code-tiles
// ---------------------------------------------------------------------------
__global__ __launch_bounds__(256) void k_final_ids(const float* __restrict__ partV,
                                                   const int* __restrict__ partI,
                                                   float* __restrict__ ids_f)
{
    const int px = blockIdx.x * 256 + threadIdx.x;   // grid 128
    float bv = partV[px]; int bi = partI[px];
#pragma unroll
    for (int ct = 1; ct < 8; ++ct) {
        float v = partV[ct * NPIX + px];
        int   i = partI[ct * NPIX + px];
        if (v < bv || (v == bv && i < bi)) { bv = v; bi = i; }
    }
    ids_f[px] = (float)bi;
}

// ===========================================================================
// FALLBACK (round-0 passing path, used if ws too small)
// ===========================================================================
__global__ __launch_bounds__(256) void k_enorm(const float* __restrict__ cb,
                                               float* __restrict__ enorm)
{
    const int tid  = threadIdx.x;
    const int lane = tid & 63;
    const int w    = tid >> 6;
    const int k    = blockIdx.x * 4 + w;
    const float* cp = cb + (size_t)k * DIM;
    float s = 0.f;
#pragma unroll
    for (int t = 0; t < 4; ++t) {
        float v = cp[lane + t * 64];
        s = fmaf(v, v, s);
    }
#pragma unroll
    for (int off = 32; off > 0; off >>= 1) s += __shfl_down(s, off);
    if (lane == 0) enorm[k] = s;
}

__global__ __launch_bounds__(256) void k_argmin(const float* __restrict__ x,
                                                const float* __restrict__ cb,
                                                const float* __restrict__ enorm,
                                                float* __restrict__ out_ids)
{
    __shared__ float xs[32][64];
    __shared__ float cbs[32][68];
    __shared__ float nx_l[64];
    __shared__ float nxp[4][64];
    __shared__ float red_v[64][17];
    __shared__ int   red_i[64][17];

    const int tid  = threadIdx.x;
    const int tx   = tid & 15;
    const int ty   = tid >> 4;
    const int pix0 = blockIdx.x * 64;
    const int b    = pix0 >> 10;
    const int hw0  = pix0 & 1023;

    {
        const int p = tid & 63, q = tid >> 6;
        float s = 0.f;
        const float* xp = x + ((size_t)(b * DIM + q * 64) * 1024) + hw0 + p;
        for (int c = 0; c < 64; ++c) {
            float v = xp[c * 1024];
            s = fmaf(v, v, s);
        }
        nxp[q][p] = s;
        __syncthreads();
        if (tid < 64)
            nx_l[tid] = ((nxp[0][tid] + nxp[1][tid]) + nxp[2][tid]) + nxp[3][tid];
        __syncthreads();
    }

    float nx_r[4];
#pragma unroll
    for (int i = 0; i < 4; ++i) nx_r[i] = nx_l[ty * 4 + i];

    float best_v[4];
    int   best_i[4];
#pragma unroll
    for (int i = 0; i < 4; ++i) { best_v[i] = 3.4e38f; best_i[i] = 0; }

    for (int cc = 0; cc < 16; ++cc) {
        float acc[4][4];
#pragma unroll
        for (int i = 0; i < 4; ++i)
#pragma unroll
            for (int j = 0; j < 4; ++j) acc[i][j] = 0.f;

        for (int kcc = 0; kcc < 8; ++kcc) {
            __syncthreads();
            {
                const int p = tid & 63, k0 = tid >> 6;
                const float* xp = x + ((size_t)(b * DIM + kcc * 32) * 1024) + hw0 + p;
#pragma unroll
                for (int tt = 0; tt < 8; ++tt) {
                    int kk = k0 + tt * 4;
                    xs[kk][p] = xp[kk * 1024];
                }
            }
            {
                const int kk = tid & 31, r0 = tid >> 5;
                const float* cp = cb + (size_t)(cc * 64) * DIM + kcc * 32 + kk;
#pragma unroll
                for (int tt = 0; tt < 8; ++tt) {
                    int r = r0 + tt * 8;
                    cbs[kk][r] = cp[r * DIM];
                }
            }
            __syncthreads();
#pragma unroll
            for (int kk = 0; kk < 32; ++kk) {
                float4 A = *(const float4*)&xs[kk][ty * 4];
                float4 B = *(const float4*)&cbs[kk][tx * 4];
                float a[4] = {A.x, A.y, A.z, A.w};
                float bb[4] = {B.x, B.y, B.z, B.w};
#pragma unroll
                for (int i = 0; i < 4; ++i)
#pragma unroll
                    for (int j = 0; j < 4; ++j)
                        acc[i][j] = fmaf(a[i], bb[j], acc[i][j]);
            }
        }

#pragma unroll
        for (int j = 0; j < 4; ++j) {
            const int code = cc * 64 + tx * 4 + j;
            const float nee = enorm[code];
#pragma unroll
            for (int i = 0; i < 4; ++i) {
                float s = (nx_r[i] + nee) - 2.0f * acc[i][j];
                if (s < best_v[i]) { best_v[i] = s; best_i[i] = code; }
            }
        }
    }

#pragma unroll
    for (int i = 0; i < 4; ++i) {
        red_v[ty * 4 + i][tx] = best_v[i];
        red_i[ty * 4 + i][tx] = best_i[i];
    }
    __syncthreads();
    if (tid < 64) {
        float bv = red_v[tid][0];
        int   bi = red_i[tid][0];
#pragma unroll
        for (int tt = 1; tt < 16; ++tt) {
            float v = red_v[tid][tt];
            int   idx = red_i[tid][tt];
            if (v < bv || (v == bv && idx < bi)) { bv = v; bi = idx; }
        }
        out_ids[pix0 + tid] = (float)bi;
    }
}

// ===========================================================================
// shared epilogue kernels
// ===========================================================================
// float4-vectorized: 4 consecutive hw elements share (b, c); ids read as float4
__global__ __launch_bounds__(256) void k_outputs(const float* __restrict__ x,
                                                 const float* __restrict__ cb,
                                                 const float* __restrict__ ids_f,
                                                 float* __restrict__ out_emb,
                                                 float* __restrict__ partials)
{
    const int tid = threadIdx.x;
    const int gid = blockIdx.x * 256 + tid;      // grid 2048
    float s = 0.f;
#pragma unroll
    for (int it = 0; it < 4; ++it) {
        const int grp = gid + it * 524288;       // float4-group index
        const int e0  = grp << 2;
        const int c   = (e0 >> 10) & 255;
        const int b   = e0 >> 18;
        const int hw  = e0 & 1023;
        const int n0  = (b << 10) + hw;
        float4 idv = *(const float4*)(ids_f + n0);
        float4 xv  = *(const float4*)(x + e0);
        float ev0 = cb[(int)idv.x * DIM + c];
        float ev1 = cb[(int)idv.y * DIM + c];
        float ev2 = cb[(int)idv.z * DIM + c];
        float ev3 = cb[(int)idv.w * DIM + c];
        float4 ov;
        ov.x = xv.x + (ev0 - xv.x);
        ov.y = xv.y + (ev1 - xv.y);
        ov.z = xv.z + (ev2 - xv.z);
        ov.w = xv.w + (ev3 - xv.w);
        *(float4*)(out_emb + e0) = ov;
        float d0 = xv.x - ev0, d1 = xv.y - ev1, d2 = xv.z - ev2, d3 = xv.w - ev3;
        s = fmaf(d0, d0, s); s = fmaf(d1, d1, s);
        s = fmaf(d2, d2, s); s = fmaf(d3, d3, s);
    }
    __shared__ float sm[256];
    sm[tid] = s;
    __syncthreads();
    for (int off = 128; off > 0; off >>= 1) {
        if (tid < off) sm[tid] += sm[tid + off];
        __syncthreads();
    }
    if (tid == 0) partials[blockIdx.x] = sm[0];
}

__global__ __launch_bounds__(256) void k_finalize(const float* __restrict__ partials,
                                                  int nparts,
                                                  float* __restrict__ out_loss)
{
    __shared__ float sm[256];
    const int tid = threadIdx.x;
    float s = 0.f;
    for (int k = tid; k < nparts; k += 256) s += partials[k];
    sm[tid] = s;
    __syncthreads();
    for (int off = 128; off > 0; off >>= 1) {
        if (tid < off) sm[tid] += sm[tid + off];
        __syncthreads();
    }
    if (tid == 0) {
        float m = sm[0] / (float)NELEM;
        out_loss[0] = m + 0.25f * m;
    }
}

// ===========================================================================
extern "C" void kernel_launch(void* const* d_in, const int* in_sizes, int n_in,
                              void* d_out, int out_size, void* d_ws, size_t ws_size,
                              hipStream_t stream)
{
    const float* x  = (const float*)d_in[0];   // (32,256,32,32)
    const float* cb = (const float*)d_in[1];   // (1024,256)
    float* out   = (float*)d_out;
    float* ids_f = out;                        // 32768
    float* emb   = out + NPIX;                 // 8388608
    float* loss  = out + NPIX + NELEM;         // 1

    char* wsb = (char*)d_ws;
    const size_t NEED = 36843520ull;
    if (ws_size >= NEED) {
        u16*   Xa = (u16*)(wsb);                     // 16 MB
        u16*   Xb = (u16*)(wsb + 16777216);          // 16 MB
        u16*   Ea = (u16*)(wsb + 33554432);          // 512 KB
        u16*   Eb = (u16*)(wsb + 34078720);          // 512 KB
        float* nx = (float*)(wsb + 34603008);        // 128 KB
        float* ne = (float*)(wsb + 34734080);        // 4 KB
        float* pV = (float*)(wsb + 34738176);        // 1 MB
        int*   pI = (int*)  (wsb + 35786752);        // 1 MB
        float* lp = (float*)(wsb + 36835328);        // 8 KB
        k_prep_x    <<<512,  256, 0, stream>>>(x, Xa, Xb, nx);
        k_prep_e    <<<128,  256, 0, stream>>>(cb, Ea, Eb, ne);
        k_mfma_argmin<<<2048, 256, 0, stream>>>(Xa, Xb, Ea, Eb, nx, ne, pV, pI);
        k_final_ids <<<128,  256, 0, stream>>>(pV, pI, ids_f);
        k_outputs   <<<2048, 256, 0, stream>>>(x, cb, ids_f, emb, lp);
        k_finalize  <<<1,    256, 0, stream>>>(lp, 2048, loss);
    } else {
        float* partials = (float*)wsb;         // 2048 floats
        float* enorm    = partials + 2048;     // 1024 floats
        k_enorm   <<<256,  256, 0, stream>>>(cb, enorm);
        k_argmin  <<<512,  256, 0, stream>>>(x, cb, enorm, ids_f);
        k_outputs <<<2048, 256, 0, stream>>>(x, cb, ids_f, emb, partials);
        k_finalize<<<1,    256, 0, stream>>>(partials, 2048, loss);
    }
}

// Round 7
// 133.490 us; speedup vs baseline: 1.3922x; 1.0746x over previous
//
#include <hip/hip_runtime.h>

#define NUM_EMB 1024
#define DIM     256
#define NPIX    32768      // 32 * 32 * 32
#define NELEM   8388608    // 32 * 256 * 32 * 32

typedef unsigned short u16;
typedef unsigned int   u32;
typedef __attribute__((ext_vector_type(8))) _Float16 f16x8;
typedef __attribute__((ext_vector_type(4))) float f32x4;

__device__ __forceinline__ u16 f32_f16(float f) {
    _Float16 h = (_Float16)f;                  // v_cvt_f16_f32, RN-even
    return __builtin_bit_cast(u16, h);
}
__device__ __forceinline__ float f16_f32(u16 b) {
    return (float)__builtin_bit_cast(_Float16, b);
}

// ===========================================================================
// MFMA path — f16 2-term split, 2 scale groups, 3 MFMA term-pairs.
//   x = 4*(Xa + 2^-10*Xb + eps), e = 2^-11*(Ea + 2^-10*Eb + eps)
//   2*x*e = 2^-8 * [S_aa + 2^-10*(S_ab + S_ba)]   (S_bb dropped, ~5e-9)
// ===========================================================================

// ---------------------------------------------------------------------------
// prep_x: split x into Xa,Xb f16 arrays, frag-major [kc8][kb4][px][8k];
// |x|^2 per pixel (fmaf chain identical to passing rounds).
// ---------------------------------------------------------------------------
__global__ __launch_bounds__(256) void k_prep_x(const float* __restrict__ x,
        u16* __restrict__ Xa, u16* __restrict__ Xb,
        float* __restrict__ nx_out)
{
    __shared__ float nxp[4][64];
    const int t  = threadIdx.x;
    const int p  = t & 63;
    const int cq = t >> 6;
    const int bi = blockIdx.x;            // 512
    const int b  = bi >> 4;
    const int hw = ((bi & 15) << 6) + p;
    const float* xp = x + (((size_t)(b * 256 + cq * 64)) << 10) + hw;
    float s = 0.f;
    for (int i0 = 0; i0 < 64; i0 += 8) {
        u32 qa[4], qb[4];
#pragma unroll
        for (int j = 0; j < 8; ++j) {
            float v = xp[(size_t)(i0 + j) << 10];
            s = fmaf(v, v, s);
            float va = v * 0.25f;                  // exact
            u16 ha = f32_f16(va);
            float rb = (va - f16_f32(ha)) * 1024.0f;   // exact (Sterbenz + pow2)
            u16 hb = f32_f16(rb);
            if ((j & 1) == 0) { qa[j>>1] = ha; qb[j>>1] = hb; }
            else { qa[j>>1] |= (u32)ha << 16; qb[j>>1] |= (u32)hb << 16; }
        }
        const int c = cq * 64 + i0;
        const size_t chunk = (((size_t)((c >> 5) * 4 + ((c >> 3) & 3))) << 15)
                             + (size_t)bi * 64 + p;
        *(uint4*)(Xa + chunk * 8) = make_uint4(qa[0], qa[1], qa[2], qa[3]);
        *(uint4*)(Xb + chunk * 8) = make_uint4(qb[0], qb[1], qb[2], qb[3]);
    }
    nxp[cq][p] = s;
    __syncthreads();
    if (t < 64)
        nx_out[bi * 64 + t] = ((nxp[0][t] + nxp[1][t]) + nxp[2][t]) + nxp[3][t];
}

// ---------------------------------------------------------------------------
// prep_e: same split for codebook -> [kc][kb][code(1024)][8k] + |e|^2
// ---------------------------------------------------------------------------
__global__ __launch_bounds__(256) void k_prep_e(const float* __restrict__ cb,
        u16* __restrict__ Ea, u16* __restrict__ Eb,
        float* __restrict__ ne_out)
{
    const int t = threadIdx.x;
    const int l32 = t & 31;
    const int code = blockIdx.x * 8 + (t >> 5);
    const float* cp = cb + (size_t)code * 256 + l32 * 8;
    u32 qa[4], qb[4];
    float s = 0.f;
#pragma unroll
    for (int j = 0; j < 8; ++j) {
        float v = cp[j];
        s = fmaf(v, v, s);
        float va = v * 2048.0f;                    // exact
        u16 ha = f32_f16(va);
        float rb = (va - f16_f32(ha)) * 1024.0f;   // exact
        u16 hb = f32_f16(rb);
        if ((j & 1) == 0) { qa[j>>1] = ha; qb[j>>1] = hb; }
        else { qa[j>>1] |= (u32)ha << 16; qb[j>>1] |= (u32)hb << 16; }
    }
    const size_t chunk = ((size_t)l32 << 10) + code;
    *(uint4*)(Ea + chunk * 8) = make_uint4(qa[0], qa[1], qa[2], qa[3]);
    *(uint4*)(Eb + chunk * 8) = make_uint4(qb[0], qb[1], qb[2], qb[3]);
#pragma unroll
    for (int off = 16; off > 0; off >>= 1) s += __shfl_xor(s, off);
    if (l32 == 0) ne_out[code] = s;
}

// ---------------------------------------------------------------------------
// MFMA distance-argmin. Round-7 structure:
//   - block 256 thr / 4 waves; tile 64 px x 128 codes; wave = 64px x 32codes
//   - acc = 16 f32x4 = 64 AGPR/wave -> launch_bounds(256,4): 4 waves/SIMD,
//     each SIMD hosts 4 waves of 4 DIFFERENT blocks (barrier-independent)
//   - A (Xa,Xb) staged once/block in LDS (global_load_lds, dbuf, 2-phase)
//   - B (Ea,Eb) global->reg, disjoint across waves, L2-resident
//   - same 3-pair f16 math as round 6 -> bit-identical scores
// ---------------------------------------------------------------------------
__global__ __launch_bounds__(256, 4) void k_mfma_argmin(
        const u16* __restrict__ XA, const u16* __restrict__ XB,
        const u16* __restrict__ EA, const u16* __restrict__ EB,
        const float* __restrict__ nx, const float* __restrict__ ne,
        float* __restrict__ partV, int* __restrict__ partI)
{
    __shared__ __align__(16) unsigned char lds[2][8192];  // A dbuf: 2 terms x 4KB
    __shared__ float redV[4][64];
    __shared__ int   redI[4][64];

    const int t = threadIdx.x;
    const int l = t & 63;
    const int w = t >> 6;

    // XCD-aware bijective swizzle (grid 4096 % 8 == 0):
    // 8 code-tile siblings of one px-tile adjacent in time on one XCD
    const int bi   = blockIdx.x;
    const int xcd  = bi & 7;
    const int slot = bi >> 3;
    const int cT   = slot & 7;
    const int pT   = ((slot >> 3) << 3) | xcd;     // [0, 512)
    const int px0  = pT << 6;                      // 64-px tile
    const int c0   = cT << 7;                      // 128-code tile
    const int n0   = w << 5;                       // wave owns 32 codes
    const int kbl  = l >> 4;
    const int il   = l & 15;

    const u16* Xt[2] = {XA, XB};

    f32x4 acc1[4][2], acc2[4][2];
#pragma unroll
    for (int i = 0; i < 4; ++i)
#pragma unroll
        for (int j = 0; j < 2; ++j) {
            acc1[i][j] = (f32x4){0.f, 0.f, 0.f, 0.f};
            acc2[i][j] = (f32x4){0.f, 0.f, 0.f, 0.f};
        }

    // B base offsets (elements); wave-disjoint code ranges
    const size_t boff = (size_t)kbl * 8192 + (size_t)(c0 + n0 + il) * 8;
    const u16* pBa = EA + boff;
    const u16* pBb = EB + boff;

    // stage A tile for K-step kc: 2 terms x 64 px x 32 d x 2B = 8 KB
    // 512 chunks of 16B; 256 threads -> 2 each; wave-linear LDS dest
    auto stageA = [&](int kc, int bf) {
#pragma unroll
        for (int h = 0; h < 2; ++h) {
            const int ci  = h * 256 + t;          // 0..511; term = h (uniform)
            const int idx = ci & 255;
            const int kb  = idx >> 6;
            const int px  = idx & 63;
            const u16* sa = Xt[h] + (((size_t)(kc * 4 + kb) << 15) + px0 + px) * 8;
            __builtin_amdgcn_global_load_lds(
                (const __attribute__((address_space(1))) void*)sa,
                (__attribute__((address_space(3))) void*)(&lds[bf][h * 4096 + idx * 16]),
                16, 0, 0);
        }
    };

    stageA(0, 0);
    __syncthreads();

#pragma unroll
    for (int kc = 0; kc < 8; ++kc) {
        const int bf = kc & 1;
        if (kc < 7) stageA(kc + 1, bf ^ 1);       // overlaps MFMA below

        // B fragments (L2): 16B/lane, 16-lane 256B segments
        f16x8 bqa[2], bqb[2];
#pragma unroll
        for (int ni = 0; ni < 2; ++ni) {
            bqa[ni] = *(const f16x8*)(pBa + (size_t)kc * 32768 + ni * 128);
            bqb[ni] = *(const f16x8*)(pBb + (size_t)kc * 32768 + ni * 128);
        }
        // A fragments from LDS
        f16x8 afa[4], afb[4];
#pragma unroll
        for (int mi = 0; mi < 4; ++mi) {
            const int fo = (kbl * 64 + mi * 16 + il) * 16;
            afa[mi] = *(const f16x8*)(&lds[bf][fo]);
            afb[mi] = *(const f16x8*)(&lds[bf][4096 + fo]);
        }
#pragma unroll
        for (int mi = 0; mi < 4; ++mi)
#pragma unroll
            for (int ni = 0; ni < 2; ++ni) {
                acc1[mi][ni] = __builtin_amdgcn_mfma_f32_16x16x32_f16(
                    afa[mi], bqa[ni], acc1[mi][ni], 0, 0, 0);
                acc2[mi][ni] = __builtin_amdgcn_mfma_f32_16x16x32_f16(
                    afb[mi], bqa[ni], acc2[mi][ni], 0, 0, 0);
                acc2[mi][ni] = __builtin_amdgcn_mfma_f32_16x16x32_f16(
                    afa[mi], bqb[ni], acc2[mi][ni], 0, 0, 0);
            }

        __syncthreads();                   // drains stage(kc+1), guards dbuf swap
    }

    // ---- epilogue: scores + argmin (C/D map: col=lane&15, row=(lane>>4)*4+r) ----
    const int g = kbl, col = il;
    float nev[2];
#pragma unroll
    for (int ni = 0; ni < 2; ++ni) nev[ni] = ne[c0 + n0 + ni * 16 + col];
#pragma unroll
    for (int mi = 0; mi < 4; ++mi) {
#pragma unroll
        for (int r = 0; r < 4; ++r) {
            const int pxl = mi * 16 + g * 4 + r;
            const float nxv = nx[px0 + pxl];
            float best = 3.4e38f; int besti = 0;
#pragma unroll
            for (int ni = 0; ni < 2; ++ni) {
                float tt = fmaf(acc2[mi][ni][r], 9.765625e-04f, acc1[mi][ni][r]);
                float sc = (nxv + nev[ni]) - tt * 3.90625e-03f;  // pow2 scale exact
                if (sc < best) { best = sc; besti = c0 + n0 + ni * 16 + col; }
            }
#pragma unroll
            for (int off = 1; off < 16; off <<= 1) {
                float ov = __shfl_xor(best, off);
                int   oi = __shfl_xor(besti, off);
                if (ov < best || (ov == best && oi < besti)) { best = ov; besti = oi; }
            }
            if (col == 0) { redV[w][pxl] = best; redI[w][pxl] = besti; }
        }
    }
    __syncthreads();
    if (t < 64) {
        float bv = redV[0][t]; int bidx = redI[0][t];
#pragma unroll
        for (int q = 1; q < 4; ++q) {
            float v = redV[q][t];
            int   i = redI[q][t];
            if (v < bv || (v == bv && i < bidx)) { bv = v; bidx = i; }
        }
        partV[cT * NPIX + px0 + t] = bv;
        partI[cT * NPIX + px0 + t] = bidx;
    }
}

// ---------------------------------------------------------------------------
// final ids: lexicographic reduce over the 8 code-tiles
// ---------------------------------------------------------------------------
__global__ __launch_bounds__(256) void k_final_ids(const float* __restrict__ partV,
                                                   const int* __restrict__ partI,
                                                   float* __restrict__ ids_f)
{
    const int px = blockIdx.x * 256 + threadIdx.x;   // grid 128
    float bv = partV[px]; int bi = partI[px];
#pragma unroll
    for (int ct = 1; ct < 8; ++ct) {
        float v = partV[ct * NPIX + px];
        int   i = partI[ct * NPIX + px];
        if (v < bv || (v == bv && i < bi)) { bv = v; bi = i; }
    }
    ids_f[px] = (float)bi;
}

// ===========================================================================
// FALLBACK (round-0 passing path, used if ws too small)
// ===========================================================================
__global__ __launch_bounds__(256) void k_enorm(const float* __restrict__ cb,
                                               float* __restrict__ enorm)
{
    const int tid  = threadIdx.x;
    const int lane = tid & 63;
    const int w    = tid >> 6;
    const int k    = blockIdx.x * 4 + w;
    const float* cp = cb + (size_t)k * DIM;
    float s = 0.f;
#pragma unroll
    for (int t = 0; t < 4; ++t) {
        float v = cp[lane + t * 64];
        s = fmaf(v, v, s);
    }
#pragma unroll
    for (int off = 32; off > 0; off >>= 1) s += __shfl_down(s, off);
    if (lane == 0) enorm[k] = s;
}

__global__ __launch_bounds__(256) void k_argmin(const float* __restrict__ x,
                                                const float* __restrict__ cb,
                                                const float* __restrict__ enorm,
                                                float* __restrict__ out_ids)
{
    __shared__ float xs[32][64];
    __shared__ float cbs[32][68];
    __shared__ float nx_l[64];
    __shared__ float nxp[4][64];
    __shared__ float red_v[64][17];
    __shared__ int   red_i[64][17];

    const int tid  = threadIdx.x;
    const int tx   = tid & 15;
    const int ty   = tid >> 4;
    const int pix0 = blockIdx.x * 64;
    const int b    = pix0 >> 10;
    const int hw0  = pix0 & 1023;

    {
        const int p = tid & 63, q = tid >> 6;
        float s = 0.f;
        const float* xp = x + ((size_t)(b * DIM + q * 64) * 1024) + hw0 + p;
        for (int c = 0; c < 64; ++c) {
            float v = xp[c * 1024];
            s = fmaf(v, v, s);
        }
        nxp[q][p] = s;
        __syncthreads();
        if (tid < 64)
            nx_l[tid] = ((nxp[0][tid] + nxp[1][tid]) + nxp[2][tid]) + nxp[3][tid];
        __syncthreads();
    }

    float nx_r[4];
#pragma unroll
    for (int i = 0; i < 4; ++i) nx_r[i] = nx_l[ty * 4 + i];

    float best_v[4];
    int   best_i[4];
#pragma unroll
    for (int i = 0; i < 4; ++i) { best_v[i] = 3.4e38f; best_i[i] = 0; }

    for (int cc = 0; cc < 16; ++cc) {
        float acc[4][4];
#pragma unroll
        for (int i = 0; i < 4; ++i)
#pragma unroll
            for (int j = 0; j < 4; ++j) acc[i][j] = 0.f;

        for (int kcc = 0; kcc < 8; ++kcc) {
            __syncthreads();
            {
                const int p = tid & 63, k0 = tid >> 6;
                const float* xp = x + ((size_t)(b * DIM + kcc * 32) * 1024) + hw0 + p;
#pragma unroll
                for (int tt = 0; tt < 8; ++tt) {
                    int kk = k0 + tt * 4;
                    xs[kk][p] = xp[kk * 1024];
                }
            }
            {
                const int kk = tid & 31, r0 = tid >> 5;
                const float* cp = cb + (size_t)(cc * 64) * DIM + kcc * 32 + kk;
#pragma unroll
                for (int tt = 0; tt < 8; ++tt) {
                    int r = r0 + tt * 8;
                    cbs[kk][r] = cp[r * DIM];
                }
            }
            __syncthreads();
#pragma unroll
            for (int kk = 0; kk < 32; ++kk) {
                float4 A = *(const float4*)&xs[kk][ty * 4];
                float4 B = *(const float4*)&cbs[kk][tx * 4];
                float a[4] = {A.x, A.y, A.z, A.w};
                float bb[4] = {B.x, B.y, B.z, B.w};
#pragma unroll
                for (int i = 0; i < 4; ++i)
#pragma unroll
                    for (int j = 0; j < 4; ++j)
                        acc[i][j] = fmaf(a[i], bb[j], acc[i][j]);
            }
        }

#pragma unroll
        for (int j = 0; j < 4; ++j) {
            const int code = cc * 64 + tx * 4 + j;
            const float nee = enorm[code];
#pragma unroll
            for (int i = 0; i < 4; ++i) {
                float s = (nx_r[i] + nee) - 2.0f * acc[i][j];
                if (s < best_v[i]) { best_v[i] = s; best_i[i] = code; }
            }
        }
    }

#pragma unroll
    for (int i = 0; i < 4; ++i) {
        red_v[ty * 4 + i][tx] = best_v[i];
        red_i[ty * 4 + i][tx] = best_i[i];
    }
    __syncthreads();
    if (tid < 64) {
        float bv = red_v[tid][0];
        int   bi = red_i[tid][0];
#pragma unroll
        for (int tt = 1; tt < 16; ++tt) {
            float v = red_v[tid][tt];
            int   idx = red_i[tid][tt];
            if (v < bv || (v == bv && idx < bi)) { bv = v; bi = idx; }
        }
        out_ids[pix0 + tid] = (float)bi;
    }
}

// ===========================================================================
// shared epilogue kernels
// ===========================================================================
__global__ __launch_bounds__(256) void k_outputs(const float* __restrict__ x,
                                                 const float* __restrict__ cb,
                                                 const float* __restrict__ ids_f,
                                                 float* __restrict__ out_emb,
                                                 float* __restrict__ partials)
{
    const int tid = threadIdx.x;
    const int gid = blockIdx.x * 256 + tid;      // grid 2048
    float s = 0.f;
#pragma unroll
    for (int it = 0; it < 4; ++it) {
        const int grp = gid + it * 524288;       // float4-group index
        const int e0  = grp << 2;
        const int c   = (e0 >> 10) & 255;
        const int b   = e0 >> 18;
        const int hw  = e0 & 1023;
        const int n0  = (b << 10) + hw;
        float4 idv = *(const float4*)(ids_f + n0);
        float4 xv  = *(const float4*)(x + e0);
        float ev0 = cb[(int)idv.x * DIM + c];
        float ev1 = cb[(int)idv.y * DIM + c];
        float ev2 = cb[(int)idv.z * DIM + c];
        float ev3 = cb[(int)idv.w * DIM + c];
        float4 ov;
        ov.x = xv.x + (ev0 - xv.x);
        ov.y = xv.y + (ev1 - xv.y);
        ov.z = xv.z + (ev2 - xv.z);
        ov.w = xv.w + (ev3 - xv.w);
        *(float4*)(out_emb + e0) = ov;
        float d0 = xv.x - ev0, d1 = xv.y - ev1, d2 = xv.z - ev2, d3 = xv.w - ev3;
        s = fmaf(d0, d0, s); s = fmaf(d1, d1, s);
        s = fmaf(d2, d2, s); s = fmaf(d3, d3, s);
    }
    __shared__ float sm[256];
    sm[tid] = s;
    __syncthreads();
    for (int off = 128; off > 0; off >>= 1) {
        if (tid < off) sm[tid] += sm[tid + off];
        __syncthreads();
    }
    if (tid == 0) partials[blockIdx.x] = sm[0];
}

__global__ __launch_bounds__(256) void k_finalize(const float* __restrict__ partials,
                                                  int nparts,
                                                  float* __restrict__ out_loss)
{
    __shared__ float sm[256];
    const int tid = threadIdx.x;
    float s = 0.f;
    for (int k = tid; k < nparts; k += 256) s += partials[k];
    sm[tid] = s;
    __syncthreads();
    for (int off = 128; off > 0; off >>= 1) {
        if (tid < off) sm[tid] += sm[tid + off];
        __syncthreads();
    }
    if (tid == 0) {
        float m = sm[0] / (float)NELEM;
        out_loss[0] = m + 0.25f * m;
    }
}

// ===========================================================================
extern "C" void kernel_launch(void* const* d_in, const int* in_sizes, int n_in,
                              void* d_out, int out_size, void* d_ws, size_t ws_size,
                              hipStream_t stream)
{
    const float* x  = (const float*)d_in[0];   // (32,256,32,32)
    const float* cb = (const float*)d_in[1];   // (1024,256)
    float* out   = (float*)d_out;
    float* ids_f = out;                        // 32768
    float* emb   = out + NPIX;                 // 8388608
    float* loss  = out + NPIX + NELEM;         // 1

    char* wsb = (char*)d_ws;
    const size_t NEED = 36843520ull;
    if (ws_size >= NEED) {
        u16*   Xa = (u16*)(wsb);                     // 16 MB
        u16*   Xb = (u16*)(wsb + 16777216);          // 16 MB
        u16*   Ea = (u16*)(wsb + 33554432);          // 512 KB
        u16*   Eb = (u16*)(wsb + 34078720);          // 512 KB
        float* nx = (float*)(wsb + 34603008);        // 128 KB
        float* ne = (float*)(wsb + 34734080);        // 4 KB
        float* pV = (float*)(wsb + 34738176);        // 1 MB
        int*   pI = (int*)  (wsb + 35786752);        // 1 MB
        float* lp = (float*)(wsb + 36835328);        // 8 KB
        k_prep_x    <<<512,  256, 0, stream>>>(x, Xa, Xb, nx);
        k_prep_e    <<<128,  256, 0, stream>>>(cb, Ea, Eb, ne);
        k_mfma_argmin<<<4096, 256, 0, stream>>>(Xa, Xb, Ea, Eb, nx, ne, pV, pI);
        k_final_ids <<<128,  256, 0, stream>>>(pV, pI, ids_f);
        k_outputs   <<<2048, 256, 0, stream>>>(x, cb, ids_f, emb, lp);
        k_finalize  <<<1,    256, 0, stream>>>(lp, 2048, loss);
    } else {
        float* partials = (float*)wsb;         // 2048 floats
        float* enorm    = partials + 2048;     // 1024 floats
        k_enorm   <<<256,  256, 0, stream>>>(cb, enorm);
        k_argmin  <<<512,  256, 0, stream>>>(x, cb, enorm, ids_f);
        k_outputs <<<2048, 256, 0, stream>>>(x, cb, ids_f, emb, partials);
        k_finalize<<<1,    256, 0, stream>>>(partials, 2048, loss);
    }
}